// Round 1
// baseline (532.087 us; speedup 1.0000x reference)
//
#include <hip/hip_runtime.h>

#define LOG2E 1.4426950408889634f

typedef _Float16 half8 __attribute__((ext_vector_type(8)));
typedef float floatx16 __attribute__((ext_vector_type(16)));

// ---- global -> LDS direct copy, 16B per lane --------------------------------
__device__ __forceinline__ void g2l16(const void* g, void* l) {
  __builtin_amdgcn_global_load_lds(
      (__attribute__((address_space(1))) void*)(unsigned long long)(g),
      (__attribute__((address_space(3))) void*)(unsigned int)(unsigned long long)(l),
      16, 0, 0);
}

// ---- prep: codebook fp32 -> fp16 (two layouts) + c2 scale -------------------
// ws layout:
//   cb16  [8][256][128] _Float16   @ 0        (512 KB)  row-major (codeword-major)
//   cbT   [8][128][256] _Float16   @ 524288   (512 KB)  d-major, codeword dim PERMUTED: k' = (k&31)*8 + (k>>5)
//   c2s   [8][256] float           @ 1048576  (8 KB)    ||c||^2 * invT * log2(e)
__global__ __launch_bounds__(128, 4) void prep_kernel(
    const float* __restrict__ cb, const int* __restrict__ tptr,
    _Float16* __restrict__ cb16, _Float16* __restrict__ cbT,
    float* __restrict__ c2s) {
  int mk = blockIdx.x;            // 0..2047 = m*256 + k
  int m = mk >> 8, k = mk & 255;
  int d = threadIdx.x;            // 0..127
  float v = cb[(size_t)mk * 128 + d];
  _Float16 h = (_Float16)v;
  cb16[(size_t)mk * 128 + d] = h;
  int kp = ((k & 31) << 3) | (k >> 5);
  cbT[((size_t)m * 128 + d) * 256 + kp] = h;
  float sq = v * v;
#pragma unroll
  for (int o = 0; o < 6; ++o) sq += __shfl_xor(sq, 1 << o, 64);
  __shared__ float part[2];
  if ((threadIdx.x & 63) == 0) part[threadIdx.x >> 6] = sq;
  __syncthreads();
  if (threadIdx.x == 0) {
    float invT = 1.0f / (float)tptr[0];
    c2s[mk] = (part[0] + part[1]) * invT * LOG2E;
  }
}

// ---- main fused kernel ------------------------------------------------------
// grid = 4096 blocks: m = blockIdx&7 (XCD-affine), row tile = blockIdx>>3 (128 rows)
// block = 256 threads = 4 waves; wave handles 32 rows, 32x32x16 f16 MFMA.
__global__ __launch_bounds__(256, 2) void pq_kernel(
    const float* __restrict__ x, const int* __restrict__ tptr,
    const _Float16* __restrict__ cb16, const _Float16* __restrict__ cbT,
    const float* __restrict__ c2s, float* __restrict__ out) {
  // LDS: bTile 8KB (shared staging buffer) + per-wave P buffer 32x264 halves
  __shared__ __align__(16) _Float16 smem[37888];  // 75776 B
  _Float16* bTile = smem;                          // 4096 halves
  _Float16* pBuf = smem + 4096;                    // 4 * 8448 halves

  const int m = blockIdx.x & 7;
  const int tile = blockIdx.x >> 3;
  const int tid = threadIdx.x;
  const int w = tid >> 6;
  const int lane = tid & 63;
  const int n2 = lane & 31;       // MFMA row (A) / col (B,D) index
  const int h = lane >> 5;        // k-half selector
  const int rowBase = tile * 128 + w * 32;
  _Float16* pw = pBuf + w * 8448;

  const _Float16* cbm = cb16 + (size_t)m * 256 * 128;
  const _Float16* cbtm = cbT + (size_t)m * 128 * 256;
  // x fragment source: row = rowBase+n2, feature base = m*128 + h*8
  const float4* xp = (const float4*)(x + (size_t)(rowBase + n2) * 1024 + m * 128 + h * 8);

  // ---------------- GEMM1: S[32 x 256] = X * C^T  (x split hi+lo fp16) ------
  floatx16 acc[8];
#pragma unroll
  for (int t = 0; t < 8; ++t)
#pragma unroll
    for (int i = 0; i < 16; ++i) acc[t][i] = 0.0f;

  for (int kc = 0; kc < 8; ++kc) {   // BK = 16 features
    // x loads for this chunk (independent of LDS tile; overlap the barriers)
    float4 xa = xp[kc * 4];
    float4 xb = xp[kc * 4 + 1];
    __syncthreads();
    // stage bTile[256 codewords][16 features] fp16 = 8 KB
#pragma unroll
    for (int i = 0; i < 2; ++i) {
      int c = i * 256 + w * 64 + lane;          // 0..511, wave-contiguous
      int n = c >> 1, part = c & 1;
      g2l16(cbm + n * 128 + kc * 16 + part * 8, bTile + c * 8);
    }
    __syncthreads();
    // build A fragments: hi + lo fp16 split of x
    float f[8] = {xa.x, xa.y, xa.z, xa.w, xb.x, xb.y, xb.z, xb.w};
    half8 ahi, alo;
#pragma unroll
    for (int j = 0; j < 8; ++j) {
      _Float16 hi = (_Float16)f[j];
      ahi[j] = hi;
      alo[j] = (_Float16)(f[j] - (float)hi);
    }
#pragma unroll
    for (int t = 0; t < 8; ++t) {
      half8 b = *(const half8*)(bTile + (t * 32 + n2) * 16 + h * 8);
      acc[t] = __builtin_amdgcn_mfma_f32_32x32x16_f16(ahi, b, acc[t], 0, 0, 0);
      acc[t] = __builtin_amdgcn_mfma_f32_32x32x16_f16(alo, b, acc[t], 0, 0, 0);
    }
  }

  // ---------------- softmax over 256 codewords per row ----------------------
  // acc[t][r] = dot for row=(r&3)+8*(r>>2)+4*h, codeword k = t*32+n2
  float invT = 1.0f / (float)tptr[0];
  float kappa = 2.0f * invT * LOG2E;
  float cc[8];
#pragma unroll
  for (int t = 0; t < 8; ++t) cc[t] = c2s[m * 256 + t * 32 + n2];
#pragma unroll
  for (int t = 0; t < 8; ++t)
#pragma unroll
    for (int r = 0; r < 16; ++r) acc[t][r] = acc[t][r] * kappa - cc[t];

#pragma unroll
  for (int r = 0; r < 16; ++r) {
    float mx = acc[0][r];
#pragma unroll
    for (int t = 1; t < 8; ++t) mx = fmaxf(mx, acc[t][r]);
#pragma unroll
    for (int o = 0; o < 5; ++o) mx = fmaxf(mx, __shfl_xor(mx, 1 << o, 64));
    float e[8];
    float s = 0.0f;
#pragma unroll
    for (int t = 0; t < 8; ++t) {
      e[t] = exp2f(acc[t][r] - mx);
      s += e[t];
    }
#pragma unroll
    for (int o = 0; o < 5; ++o) s += __shfl_xor(s, 1 << o, 64);
    float is = 1.0f / s;
    half8 p;
#pragma unroll
    for (int t = 0; t < 8; ++t) p[t] = (_Float16)(e[t] * is);
    // store P at permuted codeword index k' = n2*8 + t  -> contiguous b128
    int R = (r & 3) + 8 * (r >> 2) + 4 * h;
    *(half8*)(pw + R * 264 + n2 * 8) = p;
  }

  // ---------------- GEMM2: Out[32 x 128] = P * C  (k' permuted) -------------
  floatx16 acc2[4];
#pragma unroll
  for (int t = 0; t < 4; ++t)
#pragma unroll
    for (int i = 0; i < 16; ++i) acc2[t][i] = 0.0f;

  for (int kc = 0; kc < 8; ++kc) {   // BK = 32 codewords (k')
    // own-wave P fragments (independent of the shared tile)
    half8 a0 = *(const half8*)(pw + n2 * 264 + kc * 32 + h * 8);
    half8 a1 = *(const half8*)(pw + n2 * 264 + kc * 32 + 16 + h * 8);
    __syncthreads();
    // stage bTile[128 d][32 k'] fp16 = 8 KB
#pragma unroll
    for (int i = 0; i < 2; ++i) {
      int c = i * 256 + w * 64 + lane;          // 0..511
      int d = c >> 2, part = c & 3;
      g2l16(cbtm + d * 256 + kc * 32 + part * 8, bTile + c * 8);
    }
    __syncthreads();
#pragma unroll
    for (int dt = 0; dt < 4; ++dt) {
      half8 b0 = *(const half8*)(bTile + (dt * 32 + n2) * 32 + h * 8);
      half8 b1 = *(const half8*)(bTile + (dt * 32 + n2) * 32 + 16 + h * 8);
      acc2[dt] = __builtin_amdgcn_mfma_f32_32x32x16_f16(a0, b0, acc2[dt], 0, 0, 0);
      acc2[dt] = __builtin_amdgcn_mfma_f32_32x32x16_f16(a1, b1, acc2[dt], 0, 0, 0);
    }
  }

  // ---------------- epilogue: coalesced fp32 stores -------------------------
  float* op = out + (size_t)rowBase * 1024 + m * 128;
#pragma unroll
  for (int dt = 0; dt < 4; ++dt)
#pragma unroll
    for (int r = 0; r < 16; ++r) {
      int R = (r & 3) + 8 * (r >> 2) + 4 * h;
      op[(size_t)R * 1024 + dt * 32 + n2] = acc2[dt][r];
    }
}

extern "C" void kernel_launch(void* const* d_in, const int* in_sizes, int n_in,
                              void* d_out, int out_size, void* d_ws, size_t ws_size,
                              hipStream_t stream) {
  const float* x = (const float*)d_in[0];
  const float* cb = (const float*)d_in[1];
  const int* tptr = (const int*)d_in[2];

  _Float16* cb16 = (_Float16*)d_ws;
  _Float16* cbT = (_Float16*)((char*)d_ws + 524288);
  float* c2s = (float*)((char*)d_ws + 1048576);
  float* out = (float*)d_out;

  prep_kernel<<<2048, 128, 0, stream>>>(cb, tptr, cb16, cbT, c2s);
  pq_kernel<<<4096, 256, 0, stream>>>(x, tptr, cb16, cbT, c2s, out);
}